// Round 17
// baseline (257.969 us; speedup 1.0000x reference)
//
#include <hip/hip_runtime.h>

// Fused 3D SSIM, window 7^3, VALID. pred/targ: (4,1,32,320,320) f32.
// R16 barrier-free wave-private structure + VGPR diet to get under the
// 64-register occupancy cliff (32 waves/CU):
//  - temporal 7-ring stored as bf16x2 (v_cvt_pk_bf16_f32): 56 -> 28 VGPRs.
//    Accumulator adds/subtracts the ROUNDED value -> drift-free.
//  - int32 global offsets (buffer < 2^31 bytes).
//  - __launch_bounds__(256, 8) forces VGPR <= 64.
//  - no wsum LDS: per-wave f64 atomicAdd. LDS = 20480 B -> 8 blocks/CU.
// 2080 blocks: 16h x 26w outputs x 13 t-outputs (19 slices). Per slice:
// commit s+1 | issue loads s+2 | colsum (7x ds_read_b128) | DPP row_shr
// w-gather | bf16 ring | packed SSIM. No __syncthreads anywhere.
// Fields: f0=sum p, f1=sum q, f2=sum p^2+q^2, f3=sum p*q.

#define NPIX 343

constexpr int B = 4, T = 32, H = 320, W = 320;
constexpr int TO = T - 6, HO = H - 6, WO = W - 6;   // 26, 314, 314
constexpr long long NOUT = (long long)B * TO * HO * WO;

constexpr int TH = 16, TW = 26;    // output tile (h x w)
constexpr int NTH = 20, NTW = 13;  // 20*16 >= 314; 13*26 >= 314
constexpr int OT = 13;             // t-outputs per half

typedef float v2f __attribute__((ext_vector_type(2)));

template<int N>
__device__ __forceinline__ float row_shr(float x) {
    // lane i (within its 16-lane DPP row) receives lane i-N; OOB -> 0
    return __int_as_float(__builtin_amdgcn_update_dpp(
        0, __float_as_int(x), 0x110 | N, 0xF, 0xF, true));
}

__device__ __forceinline__ unsigned pk_bf16(v2f v) {
    unsigned r;
    asm("v_cvt_pk_bf16_f32 %0, %1, %2" : "=v"(r) : "v"(v.x), "v"(v.y));
    return r;
}
__device__ __forceinline__ v2f unpk_bf16(unsigned u) {
    v2f r;
    r.x = __uint_as_float(u << 16);
    r.y = __uint_as_float(u & 0xffff0000u);
    return r;
}

__global__ __launch_bounds__(256, 8) void ssim3d_fused(
    const float* __restrict__ pred,
    const float* __restrict__ targ,
    const float* __restrict__ drange,
    double* __restrict__ acc)
{
    __shared__ float4 swv[4][2][10][16];   // 20480 B, wave-private regions

    const int bx = blockIdx.x;
    const int b  = bx / (2 * NTH * NTW);
    int rem      = bx % (2 * NTH * NTW);
    const int half = rem / (NTH * NTW);
    rem          = rem % (NTH * NTW);
    const int h0 = (rem / NTW) * TH;
    const int w0 = (rem % NTW) * TW;
    const int t0 = half * OT;

    const int tid  = threadIdx.x;
    const int wv   = tid >> 6;    // wave 0..3
    const int lane = tid & 63;
    const int ohl  = lane >> 4;   // 0..3: output row within wave
    const int k    = lane & 15;   // pair-column 0..15
    const int h0w  = h0 + 4 * wv; // wave's first output row

    const float* pb = pred + b * (T * H * W);
    const float* qb = targ + b * (T * H * W);

    // ---- wave-private staging: 160 items = 10 rows x 16 pair-cols ----
    // lane handles items lane, lane+64, (lane<32: lane+128)
    const bool has2 = (lane < 32);
    auto gofs = [&](int i) {
        int r = min(h0w + (i >> 4), H - 1);
        int c = min(w0 + 2 * (i & 15), W - 2);
        return r * W + c;
    };
    const int ga0 = gofs(lane);
    const int ga1 = gofs(lane + 64);
    const int ga2 = has2 ? gofs(lane + 128) : 0;

    float2 p0, q0, p1, q1, p2, q2;
    auto loadw = [&](int s) {
        const int so = (t0 + s) * (H * W);
        p0 = *reinterpret_cast<const float2*>(pb + so + ga0);
        q0 = *reinterpret_cast<const float2*>(qb + so + ga0);
        p1 = *reinterpret_cast<const float2*>(pb + so + ga1);
        q1 = *reinterpret_cast<const float2*>(qb + so + ga1);
        if (has2) {
            p2 = *reinterpret_cast<const float2*>(pb + so + ga2);
            q2 = *reinterpret_cast<const float2*>(qb + so + ga2);
        }
    };
    auto commitw = [&](int buf) {
        swv[wv][buf][ohl][k]     = make_float4(p0.x, p0.y, q0.x, q0.y);
        swv[wv][buf][4 + ohl][k] = make_float4(p1.x, p1.y, q1.x, q1.y);
        if (has2)
            swv[wv][buf][8 + ohl][k] = make_float4(p2.x, p2.y, q2.x, q2.y);
    };

    // ---- output mapping: thread k emits local cols 2k-6 (even), 2k-5 (odd)
    const bool vh = (h0w + ohl < HO);
    const bool k3 = (k >= 3);
    const bool vE = k3 && vh && (w0 + 2 * k - 6 < WO);
    const bool vO = k3 && vh && (w0 + 2 * k - 5 < WO);

    const float dr  = drange[b];
    const float C1s = (0.01f * dr) * (0.01f * dr);
    const float C2s = (0.03f * dr) * (0.03f * dr);
    const float inv  = 1.0f / (float)NPIX;
    const float covn = (float)NPIX / (float)(NPIX - 1);
    const v2f invv  = {inv, inv};
    const v2f C1vv  = {C1s, C1s};
    const v2f C2vv  = {C2s, C2s};
    const v2f covnv = {covn, covn};
    const v2f c2cov = {2.f * covn, 2.f * covn};

    unsigned rg[4][7];   // bf16x2-packed temporal ring
    v2f tEO[4];
#pragma unroll
    for (int f = 0; f < 4; ++f) {
        tEO[f] = (v2f){0.f, 0.f};
#pragma unroll
        for (int j = 0; j < 7; ++j) rg[f][j] = 0u;
    }
    float loss = 0.f;

    // ---- one slice; jj and flags compile-time at every call site ----
    auto slice = [&](int s, int jj, bool doEmit, bool doCommit, bool doPrefetch) {
        if (doCommit)  commitw((s + 1) & 1);  // regs loaded at slice s-1
        if (doPrefetch) loadw(s + 2);         // consumed at slice s+1

        // ---- per-thread pair-colsum: cols (2k,2k+1), rows ohl..ohl+6 ----
        const int bs = s & 1;
        v2f c0 = {0.f, 0.f}, c1v = {0.f, 0.f}, c2 = {0.f, 0.f}, c3 = {0.f, 0.f};
#pragma unroll
        for (int dy = 0; dy < 7; ++dy) {
            float4 v = swv[wv][bs][ohl + dy][k];
            v2f vp = {v.x, v.y};
            v2f vq = {v.z, v.w};
            c0 += vp;
            c1v += vq;
            c2 = __builtin_elementwise_fma(vp, vp, c2);
            c2 = __builtin_elementwise_fma(vq, vq, c2);
            c3 = __builtin_elementwise_fma(vp, vq, c3);
        }

        // ---- in-register w-gather via DPP row_shr ----
        v2f sv[4];
        {
            v2f cf[4] = {c0, c1v, c2, c3};
#pragma unroll
            for (int f = 0; f < 4; ++f) {
                float ps = cf[f].x + cf[f].y;
                float t1 = ps + row_shr<1>(ps);
                float s8 = t1 + row_shr<2>(t1);      // pairs k-3..k
                float eL = row_shr<3>(cf[f].x);      // col 2k-6
                sv[f].x = s8 - cf[f].y;              // cols 2k-6..2k (even)
                sv[f].y = s8 - eL;                   // cols 2k-5..2k+1 (odd)
            }
        }

        // ---- temporal 7-ring (slot jj = s % 7), bf16x2-packed ----
#pragma unroll
        for (int f = 0; f < 4; ++f) {
            unsigned nw = pk_bf16(sv[f]);
            v2f svr = unpk_bf16(nw);      // the value actually accumulated
            v2f old = unpk_bf16(rg[f][jj]);
            tEO[f] += svr - old;
            rg[f][jj] = nw;
        }

        // ---- SSIM on packed (E,O), emit for t_out = t0 + s - 6 ----
        if (doEmit) {
            v2f ux  = tEO[0] * invv;
            v2f uy  = tEO[1] * invv;
            v2f u2  = tEO[2] * invv;
            v2f uxy = tEO[3] * invv;
            v2f m   = __builtin_elementwise_fma(-ux, uy, uxy);
            v2f A2  = __builtin_elementwise_fma(c2cov, m, C2vv);
            v2f nb  = __builtin_elementwise_fma(-ux, ux, u2);
            nb      = __builtin_elementwise_fma(-uy, uy, nb);
            v2f B2  = __builtin_elementwise_fma(covnv, nb, C2vv);
            v2f ux2 = ux + ux;
            v2f A1  = __builtin_elementwise_fma(ux2, uy, C1vv);
            v2f B1  = __builtin_elementwise_fma(
                          ux, ux, __builtin_elementwise_fma(uy, uy, C1vv));
            v2f num = A1 * A2;
            v2f den = B1 * B2;
            float sx = __fdividef(num.x, den.x);
            float sy = __fdividef(num.y, den.y);
            if (vE) loss += 1.f - sx;
            if (vO) loss += 1.f - sy;
        }
    };

    // ---- prologue (wave-local, no barrier) ----
    loadw(0);
    commitw(0);
    loadw(1);

    // slices 0..6: ring fill, emit only at s==6 (s+2 <= 8 < 19)
#pragma unroll
    for (int jj = 0; jj < 7; ++jj)
        slice(jj, jj, jj == 6, true, true);

    // slices 7..13: unconditional (s+2 <= 15 < 19)
#pragma unroll
    for (int jj = 0; jj < 7; ++jj)
        slice(7 + jj, jj, true, true, true);

    // tail: s = 14..18 (flags compile-time)
    slice(14, 0, true, true, true);    // commit 15, load 16
    slice(15, 1, true, true, true);    // commit 16, load 17
    slice(16, 2, true, true, true);    // commit 17, load 18
    slice(17, 3, true, true, false);   // commit 18
    slice(18, 4, true, false, false);

    // ---- wave reduction -> per-wave global atomic (no barrier) ----
    for (int off = 32; off > 0; off >>= 1)
        loss += __shfl_down(loss, off, 64);
    if (lane == 0) atomicAdd(acc, (double)loss);
}

__global__ void ssim3d_finalize(const double* __restrict__ acc,
                                float* __restrict__ out)
{
    out[0] = (float)(acc[0] / (double)NOUT);
}

extern "C" void kernel_launch(void* const* d_in, const int* in_sizes, int n_in,
                              void* d_out, int out_size, void* d_ws, size_t ws_size,
                              hipStream_t stream)
{
    const float* pred   = (const float*)d_in[0];
    const float* targ   = (const float*)d_in[1];
    const float* drange = (const float*)d_in[2];
    float* out  = (float*)d_out;
    double* acc = (double*)d_ws;

    hipMemsetAsync(acc, 0, sizeof(double), stream);

    const int nblocks = B * 2 * NTH * NTW;  // 2080
    ssim3d_fused<<<nblocks, 256, 0, stream>>>(pred, targ, drange, acc);
    ssim3d_finalize<<<1, 1, 0, stream>>>(acc, out);
}

// Round 18
// 139.029 us; speedup vs baseline: 1.8555x; 1.8555x over previous
//
#include <hip/hip_runtime.h>

// Fused 3D SSIM, window 7^3, VALID. pred/targ: (4,1,32,320,320) f32.
// R16 barrier-free wave-private structure + NATURAL VGPR diet (no forced
// launch bounds -- R17's (256,8) caused VGPR=32 + spills):
//  - temporal 7-ring stored as bf16x2 (v_cvt_pk_bf16_f32): -28 VGPR.
//    Accumulator adds/subtracts the ROUNDED value -> drift-free.
//    (Numerics verified in R17: passed with absmax 0.)
//  - int32 global offsets (buffer < 2^31 bytes).
//  - no wsum LDS: per-wave f64 atomicAdd; LDS = 20480 B = 160KiB/8 exactly.
// Goal: VGPR <= 64 naturally -> 8 waves/SIMD -> 8 blocks/CU; grid 2080 =
// 8.1 blocks/CU demand. 2080 blocks: 16h x 26w outputs x 13 t-outputs
// (19 slices). Per slice: commit s+1 | issue loads s+2 | colsum (7x
// ds_read_b128) | DPP row_shr w-gather | bf16 ring | packed SSIM.
// No __syncthreads in the main loop.
// Fields: f0=sum p, f1=sum q, f2=sum p^2+q^2, f3=sum p*q.

#define NPIX 343

constexpr int B = 4, T = 32, H = 320, W = 320;
constexpr int TO = T - 6, HO = H - 6, WO = W - 6;   // 26, 314, 314
constexpr long long NOUT = (long long)B * TO * HO * WO;

constexpr int TH = 16, TW = 26;    // output tile (h x w)
constexpr int NTH = 20, NTW = 13;  // 20*16 >= 314; 13*26 >= 314
constexpr int OT = 13;             // t-outputs per half

typedef float v2f __attribute__((ext_vector_type(2)));

template<int N>
__device__ __forceinline__ float row_shr(float x) {
    // lane i (within its 16-lane DPP row) receives lane i-N; OOB -> 0
    return __int_as_float(__builtin_amdgcn_update_dpp(
        0, __float_as_int(x), 0x110 | N, 0xF, 0xF, true));
}

__device__ __forceinline__ unsigned pk_bf16(v2f v) {
    unsigned r;
    asm("v_cvt_pk_bf16_f32 %0, %1, %2" : "=v"(r) : "v"(v.x), "v"(v.y));
    return r;
}
__device__ __forceinline__ v2f unpk_bf16(unsigned u) {
    v2f r;
    r.x = __uint_as_float(u << 16);
    r.y = __uint_as_float(u & 0xffff0000u);
    return r;
}

__global__ __launch_bounds__(256) void ssim3d_fused(
    const float* __restrict__ pred,
    const float* __restrict__ targ,
    const float* __restrict__ drange,
    double* __restrict__ acc)
{
    __shared__ float4 swv[4][2][10][16];   // 20480 B, wave-private regions

    const int bx = blockIdx.x;
    const int b  = bx / (2 * NTH * NTW);
    int rem      = bx % (2 * NTH * NTW);
    const int half = rem / (NTH * NTW);
    rem          = rem % (NTH * NTW);
    const int h0 = (rem / NTW) * TH;
    const int w0 = (rem % NTW) * TW;
    const int t0 = half * OT;

    const int tid  = threadIdx.x;
    const int wv   = tid >> 6;    // wave 0..3
    const int lane = tid & 63;
    const int ohl  = lane >> 4;   // 0..3: output row within wave
    const int k    = lane & 15;   // pair-column 0..15
    const int h0w  = h0 + 4 * wv; // wave's first output row

    const float* pb = pred + b * (T * H * W);
    const float* qb = targ + b * (T * H * W);

    // ---- wave-private staging: 160 items = 10 rows x 16 pair-cols ----
    // lane handles items lane, lane+64, (lane<32: lane+128)
    const bool has2 = (lane < 32);
    auto gofs = [&](int i) {
        int r = min(h0w + (i >> 4), H - 1);
        int c = min(w0 + 2 * (i & 15), W - 2);
        return r * W + c;
    };
    const int ga0 = gofs(lane);
    const int ga1 = gofs(lane + 64);
    const int ga2 = has2 ? gofs(lane + 128) : 0;

    float2 p0, q0, p1, q1, p2, q2;
    auto loadw = [&](int s) {
        const int so = (t0 + s) * (H * W);
        p0 = *reinterpret_cast<const float2*>(pb + so + ga0);
        q0 = *reinterpret_cast<const float2*>(qb + so + ga0);
        p1 = *reinterpret_cast<const float2*>(pb + so + ga1);
        q1 = *reinterpret_cast<const float2*>(qb + so + ga1);
        if (has2) {
            p2 = *reinterpret_cast<const float2*>(pb + so + ga2);
            q2 = *reinterpret_cast<const float2*>(qb + so + ga2);
        }
    };
    auto commitw = [&](int buf) {
        swv[wv][buf][ohl][k]     = make_float4(p0.x, p0.y, q0.x, q0.y);
        swv[wv][buf][4 + ohl][k] = make_float4(p1.x, p1.y, q1.x, q1.y);
        if (has2)
            swv[wv][buf][8 + ohl][k] = make_float4(p2.x, p2.y, q2.x, q2.y);
    };

    // ---- output mapping: thread k emits local cols 2k-6 (even), 2k-5 (odd)
    const bool vh = (h0w + ohl < HO);
    const bool k3 = (k >= 3);
    const bool vE = k3 && vh && (w0 + 2 * k - 6 < WO);
    const bool vO = k3 && vh && (w0 + 2 * k - 5 < WO);

    const float dr  = drange[b];
    const float C1s = (0.01f * dr) * (0.01f * dr);
    const float C2s = (0.03f * dr) * (0.03f * dr);
    const float inv  = 1.0f / (float)NPIX;
    const float covn = (float)NPIX / (float)(NPIX - 1);
    const v2f invv  = {inv, inv};
    const v2f C1vv  = {C1s, C1s};
    const v2f C2vv  = {C2s, C2s};
    const v2f covnv = {covn, covn};
    const v2f c2cov = {2.f * covn, 2.f * covn};

    unsigned rg[4][7];   // bf16x2-packed temporal ring
    v2f tEO[4];
#pragma unroll
    for (int f = 0; f < 4; ++f) {
        tEO[f] = (v2f){0.f, 0.f};
#pragma unroll
        for (int j = 0; j < 7; ++j) rg[f][j] = 0u;
    }
    float loss = 0.f;

    // ---- one slice; jj and flags compile-time at every call site ----
    auto slice = [&](int s, int jj, bool doEmit, bool doCommit, bool doPrefetch) {
        if (doCommit)  commitw((s + 1) & 1);  // regs loaded at slice s-1
        if (doPrefetch) loadw(s + 2);         // consumed at slice s+1

        // ---- per-thread pair-colsum: cols (2k,2k+1), rows ohl..ohl+6 ----
        const int bs = s & 1;
        v2f c0 = {0.f, 0.f}, c1v = {0.f, 0.f}, c2 = {0.f, 0.f}, c3 = {0.f, 0.f};
#pragma unroll
        for (int dy = 0; dy < 7; ++dy) {
            float4 v = swv[wv][bs][ohl + dy][k];
            v2f vp = {v.x, v.y};
            v2f vq = {v.z, v.w};
            c0 += vp;
            c1v += vq;
            c2 = __builtin_elementwise_fma(vp, vp, c2);
            c2 = __builtin_elementwise_fma(vq, vq, c2);
            c3 = __builtin_elementwise_fma(vp, vq, c3);
        }

        // ---- in-register w-gather via DPP row_shr ----
        v2f sv[4];
        {
            v2f cf[4] = {c0, c1v, c2, c3};
#pragma unroll
            for (int f = 0; f < 4; ++f) {
                float ps = cf[f].x + cf[f].y;
                float t1 = ps + row_shr<1>(ps);
                float s8 = t1 + row_shr<2>(t1);      // pairs k-3..k
                float eL = row_shr<3>(cf[f].x);      // col 2k-6
                sv[f].x = s8 - cf[f].y;              // cols 2k-6..2k (even)
                sv[f].y = s8 - eL;                   // cols 2k-5..2k+1 (odd)
            }
        }

        // ---- temporal 7-ring (slot jj = s % 7), bf16x2-packed ----
#pragma unroll
        for (int f = 0; f < 4; ++f) {
            unsigned nw = pk_bf16(sv[f]);
            v2f svr = unpk_bf16(nw);      // the value actually accumulated
            v2f old = unpk_bf16(rg[f][jj]);
            tEO[f] += svr - old;
            rg[f][jj] = nw;
        }

        // ---- SSIM on packed (E,O), emit for t_out = t0 + s - 6 ----
        if (doEmit) {
            v2f ux  = tEO[0] * invv;
            v2f uy  = tEO[1] * invv;
            v2f u2  = tEO[2] * invv;
            v2f uxy = tEO[3] * invv;
            v2f m   = __builtin_elementwise_fma(-ux, uy, uxy);
            v2f A2  = __builtin_elementwise_fma(c2cov, m, C2vv);
            v2f nb  = __builtin_elementwise_fma(-ux, ux, u2);
            nb      = __builtin_elementwise_fma(-uy, uy, nb);
            v2f B2  = __builtin_elementwise_fma(covnv, nb, C2vv);
            v2f ux2 = ux + ux;
            v2f A1  = __builtin_elementwise_fma(ux2, uy, C1vv);
            v2f B1  = __builtin_elementwise_fma(
                          ux, ux, __builtin_elementwise_fma(uy, uy, C1vv));
            v2f num = A1 * A2;
            v2f den = B1 * B2;
            float sx = __fdividef(num.x, den.x);
            float sy = __fdividef(num.y, den.y);
            if (vE) loss += 1.f - sx;
            if (vO) loss += 1.f - sy;
        }
    };

    // ---- prologue (wave-local, no barrier) ----
    loadw(0);
    commitw(0);
    loadw(1);

    // slices 0..6: ring fill, emit only at s==6 (s+2 <= 8 < 19)
#pragma unroll
    for (int jj = 0; jj < 7; ++jj)
        slice(jj, jj, jj == 6, true, true);

    // slices 7..13: unconditional (s+2 <= 15 < 19)
#pragma unroll
    for (int jj = 0; jj < 7; ++jj)
        slice(7 + jj, jj, true, true, true);

    // tail: s = 14..18 (flags compile-time)
    slice(14, 0, true, true, true);    // commit 15, load 16
    slice(15, 1, true, true, true);    // commit 16, load 17
    slice(16, 2, true, true, true);    // commit 17, load 18
    slice(17, 3, true, true, false);   // commit 18
    slice(18, 4, true, false, false);

    // ---- wave reduction -> per-wave global atomic (no barrier) ----
    for (int off = 32; off > 0; off >>= 1)
        loss += __shfl_down(loss, off, 64);
    if (lane == 0) atomicAdd(acc, (double)loss);
}

__global__ void ssim3d_finalize(const double* __restrict__ acc,
                                float* __restrict__ out)
{
    out[0] = (float)(acc[0] / (double)NOUT);
}

extern "C" void kernel_launch(void* const* d_in, const int* in_sizes, int n_in,
                              void* d_out, int out_size, void* d_ws, size_t ws_size,
                              hipStream_t stream)
{
    const float* pred   = (const float*)d_in[0];
    const float* targ   = (const float*)d_in[1];
    const float* drange = (const float*)d_in[2];
    float* out  = (float*)d_out;
    double* acc = (double*)d_ws;

    hipMemsetAsync(acc, 0, sizeof(double), stream);

    const int nblocks = B * 2 * NTH * NTW;  // 2080
    ssim3d_fused<<<nblocks, 256, 0, stream>>>(pred, targ, drange, acc);
    ssim3d_finalize<<<1, 1, 0, stream>>>(acc, out);
}

// Round 19
// 135.286 us; speedup vs baseline: 1.9068x; 1.0277x over previous
//
#include <hip/hip_runtime.h>

// Fused 3D SSIM, window 7^3, VALID. pred/targ: (4,1,32,320,320) f32.
// R18 structure with the inline-asm cvt_pk REMOVED (m240: asm cvt_pk is a
// scheduling barrier, -37%): bf16 ring packed via plain-C RTNE (shift/add).
// Barrier-free wave-private staging; int32 offsets; per-wave f64 atomic;
// LDS = 20480 B (8 blocks/CU); target VGPR <= 64 (8 waves/SIMD).
// 2080 blocks: 16h x 26w outputs x 13 t-outputs (19 slices). Per slice:
// commit s+1 | issue loads s+2 | colsum (7x ds_read_b128) | DPP row_shr
// w-gather | bf16 ring (plain-C pack) | packed SSIM. No __syncthreads in
// the main loop. Fields: f0=sum p, f1=sum q, f2=sum p^2+q^2, f3=sum p*q.

#define NPIX 343

constexpr int B = 4, T = 32, H = 320, W = 320;
constexpr int TO = T - 6, HO = H - 6, WO = W - 6;   // 26, 314, 314
constexpr long long NOUT = (long long)B * TO * HO * WO;

constexpr int TH = 16, TW = 26;    // output tile (h x w)
constexpr int NTH = 20, NTW = 13;  // 20*16 >= 314; 13*26 >= 314
constexpr int OT = 13;             // t-outputs per half

typedef float v2f __attribute__((ext_vector_type(2)));

template<int N>
__device__ __forceinline__ float row_shr(float x) {
    // lane i (within its 16-lane DPP row) receives lane i-N; OOB -> 0
    return __int_as_float(__builtin_amdgcn_update_dpp(
        0, __float_as_int(x), 0x110 | N, 0xF, 0xF, true));
}

// plain-C RTNE f32->bf16x2 pack (no inline asm -- m240: asm kills scheduling)
__device__ __forceinline__ unsigned pk_bf16(v2f v) {
    unsigned bx = __float_as_uint(v.x);
    unsigned by = __float_as_uint(v.y);
    bx += 0x7fffu + ((bx >> 16) & 1u);
    by += 0x7fffu + ((by >> 16) & 1u);
    return (bx >> 16) | (by & 0xffff0000u);
}
__device__ __forceinline__ v2f unpk_bf16(unsigned u) {
    v2f r;
    r.x = __uint_as_float(u << 16);
    r.y = __uint_as_float(u & 0xffff0000u);
    return r;
}

__global__ __launch_bounds__(256) void ssim3d_fused(
    const float* __restrict__ pred,
    const float* __restrict__ targ,
    const float* __restrict__ drange,
    double* __restrict__ acc)
{
    __shared__ float4 swv[4][2][10][16];   // 20480 B, wave-private regions

    const int bx = blockIdx.x;
    const int b  = bx / (2 * NTH * NTW);
    int rem      = bx % (2 * NTH * NTW);
    const int half = rem / (NTH * NTW);
    rem          = rem % (NTH * NTW);
    const int h0 = (rem / NTW) * TH;
    const int w0 = (rem % NTW) * TW;
    const int t0 = half * OT;

    const int tid  = threadIdx.x;
    const int wv   = tid >> 6;    // wave 0..3
    const int lane = tid & 63;
    const int ohl  = lane >> 4;   // 0..3: output row within wave
    const int k    = lane & 15;   // pair-column 0..15
    const int h0w  = h0 + 4 * wv; // wave's first output row

    const float* pb = pred + b * (T * H * W);
    const float* qb = targ + b * (T * H * W);

    // ---- wave-private staging: 160 items = 10 rows x 16 pair-cols ----
    // lane handles items lane, lane+64, (lane<32: lane+128)
    const bool has2 = (lane < 32);
    auto gofs = [&](int i) {
        int r = min(h0w + (i >> 4), H - 1);
        int c = min(w0 + 2 * (i & 15), W - 2);
        return r * W + c;
    };
    const int ga0 = gofs(lane);
    const int ga1 = gofs(lane + 64);
    const int ga2 = has2 ? gofs(lane + 128) : 0;

    float2 p0, q0, p1, q1, p2, q2;
    auto loadw = [&](int s) {
        const int so = (t0 + s) * (H * W);
        p0 = *reinterpret_cast<const float2*>(pb + so + ga0);
        q0 = *reinterpret_cast<const float2*>(qb + so + ga0);
        p1 = *reinterpret_cast<const float2*>(pb + so + ga1);
        q1 = *reinterpret_cast<const float2*>(qb + so + ga1);
        if (has2) {
            p2 = *reinterpret_cast<const float2*>(pb + so + ga2);
            q2 = *reinterpret_cast<const float2*>(qb + so + ga2);
        }
    };
    auto commitw = [&](int buf) {
        swv[wv][buf][ohl][k]     = make_float4(p0.x, p0.y, q0.x, q0.y);
        swv[wv][buf][4 + ohl][k] = make_float4(p1.x, p1.y, q1.x, q1.y);
        if (has2)
            swv[wv][buf][8 + ohl][k] = make_float4(p2.x, p2.y, q2.x, q2.y);
    };

    // ---- output mapping: thread k emits local cols 2k-6 (even), 2k-5 (odd)
    const bool vh = (h0w + ohl < HO);
    const bool k3 = (k >= 3);
    const bool vE = k3 && vh && (w0 + 2 * k - 6 < WO);
    const bool vO = k3 && vh && (w0 + 2 * k - 5 < WO);

    const float dr  = drange[b];
    const float C1s = (0.01f * dr) * (0.01f * dr);
    const float C2s = (0.03f * dr) * (0.03f * dr);
    const float inv  = 1.0f / (float)NPIX;
    const float covn = (float)NPIX / (float)(NPIX - 1);
    const v2f invv  = {inv, inv};
    const v2f C1vv  = {C1s, C1s};
    const v2f C2vv  = {C2s, C2s};
    const v2f covnv = {covn, covn};
    const v2f c2cov = {2.f * covn, 2.f * covn};

    unsigned rg[4][7];   // bf16x2-packed temporal ring
    v2f tEO[4];
#pragma unroll
    for (int f = 0; f < 4; ++f) {
        tEO[f] = (v2f){0.f, 0.f};
#pragma unroll
        for (int j = 0; j < 7; ++j) rg[f][j] = 0u;
    }
    float loss = 0.f;

    // ---- one slice; jj and flags compile-time at every call site ----
    auto slice = [&](int s, int jj, bool doEmit, bool doCommit, bool doPrefetch) {
        if (doCommit)  commitw((s + 1) & 1);  // regs loaded at slice s-1
        if (doPrefetch) loadw(s + 2);         // consumed at slice s+1

        // ---- per-thread pair-colsum: cols (2k,2k+1), rows ohl..ohl+6 ----
        const int bs = s & 1;
        v2f c0 = {0.f, 0.f}, c1v = {0.f, 0.f}, c2 = {0.f, 0.f}, c3 = {0.f, 0.f};
#pragma unroll
        for (int dy = 0; dy < 7; ++dy) {
            float4 v = swv[wv][bs][ohl + dy][k];
            v2f vp = {v.x, v.y};
            v2f vq = {v.z, v.w};
            c0 += vp;
            c1v += vq;
            c2 = __builtin_elementwise_fma(vp, vp, c2);
            c2 = __builtin_elementwise_fma(vq, vq, c2);
            c3 = __builtin_elementwise_fma(vp, vq, c3);
        }

        // ---- in-register w-gather via DPP row_shr ----
        v2f sv[4];
        {
            v2f cf[4] = {c0, c1v, c2, c3};
#pragma unroll
            for (int f = 0; f < 4; ++f) {
                float ps = cf[f].x + cf[f].y;
                float t1 = ps + row_shr<1>(ps);
                float s8 = t1 + row_shr<2>(t1);      // pairs k-3..k
                float eL = row_shr<3>(cf[f].x);      // col 2k-6
                sv[f].x = s8 - cf[f].y;              // cols 2k-6..2k (even)
                sv[f].y = s8 - eL;                   // cols 2k-5..2k+1 (odd)
            }
        }

        // ---- temporal 7-ring (slot jj = s % 7), bf16x2-packed ----
#pragma unroll
        for (int f = 0; f < 4; ++f) {
            unsigned nw = pk_bf16(sv[f]);
            v2f svr = unpk_bf16(nw);      // the value actually accumulated
            v2f old = unpk_bf16(rg[f][jj]);
            tEO[f] += svr - old;
            rg[f][jj] = nw;
        }

        // ---- SSIM on packed (E,O), emit for t_out = t0 + s - 6 ----
        if (doEmit) {
            v2f ux  = tEO[0] * invv;
            v2f uy  = tEO[1] * invv;
            v2f u2  = tEO[2] * invv;
            v2f uxy = tEO[3] * invv;
            v2f m   = __builtin_elementwise_fma(-ux, uy, uxy);
            v2f A2  = __builtin_elementwise_fma(c2cov, m, C2vv);
            v2f nb  = __builtin_elementwise_fma(-ux, ux, u2);
            nb      = __builtin_elementwise_fma(-uy, uy, nb);
            v2f B2  = __builtin_elementwise_fma(covnv, nb, C2vv);
            v2f ux2 = ux + ux;
            v2f A1  = __builtin_elementwise_fma(ux2, uy, C1vv);
            v2f B1  = __builtin_elementwise_fma(
                          ux, ux, __builtin_elementwise_fma(uy, uy, C1vv));
            v2f num = A1 * A2;
            v2f den = B1 * B2;
            float sx = __fdividef(num.x, den.x);
            float sy = __fdividef(num.y, den.y);
            if (vE) loss += 1.f - sx;
            if (vO) loss += 1.f - sy;
        }
    };

    // ---- prologue (wave-local, no barrier) ----
    loadw(0);
    commitw(0);
    loadw(1);

    // slices 0..6: ring fill, emit only at s==6 (s+2 <= 8 < 19)
#pragma unroll
    for (int jj = 0; jj < 7; ++jj)
        slice(jj, jj, jj == 6, true, true);

    // slices 7..13: unconditional (s+2 <= 15 < 19)
#pragma unroll
    for (int jj = 0; jj < 7; ++jj)
        slice(7 + jj, jj, true, true, true);

    // tail: s = 14..18 (flags compile-time)
    slice(14, 0, true, true, true);    // commit 15, load 16
    slice(15, 1, true, true, true);    // commit 16, load 17
    slice(16, 2, true, true, true);    // commit 17, load 18
    slice(17, 3, true, true, false);   // commit 18
    slice(18, 4, true, false, false);

    // ---- wave reduction -> per-wave global atomic (no barrier) ----
    for (int off = 32; off > 0; off >>= 1)
        loss += __shfl_down(loss, off, 64);
    if (lane == 0) atomicAdd(acc, (double)loss);
}

__global__ void ssim3d_finalize(const double* __restrict__ acc,
                                float* __restrict__ out)
{
    out[0] = (float)(acc[0] / (double)NOUT);
}

extern "C" void kernel_launch(void* const* d_in, const int* in_sizes, int n_in,
                              void* d_out, int out_size, void* d_ws, size_t ws_size,
                              hipStream_t stream)
{
    const float* pred   = (const float*)d_in[0];
    const float* targ   = (const float*)d_in[1];
    const float* drange = (const float*)d_in[2];
    float* out  = (float*)d_out;
    double* acc = (double*)d_ws;

    hipMemsetAsync(acc, 0, sizeof(double), stream);

    const int nblocks = B * 2 * NTH * NTW;  // 2080
    ssim3d_fused<<<nblocks, 256, 0, stream>>>(pred, targ, drange, acc);
    ssim3d_finalize<<<1, 1, 0, stream>>>(acc, out);
}

// Round 20
// 73.503 us; speedup vs baseline: 3.5097x; 1.8406x over previous
//
#include <hip/hip_runtime.h>

// Fused 3D SSIM, window 7^3, VALID. pred/targ: (4,1,32,320,320) f32.
// R18 structure (barrier-free wave-private staging, bf16x2-packed temporal
// ring via v_cvt_pk_bf16_f32 -> VGPR 56 (under the 64 cliff: 8 waves/SIMD),
// LDS 20480 B = exactly 8 blocks/CU, 2080 blocks ~ 8.1/CU) with the
// reduction made ATOMIC-FREE: R18/R19's 2x regression matched the ~60us
// serialization tail of 8320 same-address f64 atomics, not the bf16 ring.
// Each wave plain-stores its f32 partial to ws[bx*4+wv]; a finalize kernel
// sums the 8320 partials. All ws slots written every launch (deterministic).
// Per slice: commit s+1 | issue loads s+2 | colsum (7x ds_read_b128) |
// DPP row_shr w-gather | bf16 ring | packed SSIM. No __syncthreads at all.
// Fields: f0=sum p, f1=sum q, f2=sum p^2+q^2, f3=sum p*q.

#define NPIX 343

constexpr int B = 4, T = 32, H = 320, W = 320;
constexpr int TO = T - 6, HO = H - 6, WO = W - 6;   // 26, 314, 314
constexpr long long NOUT = (long long)B * TO * HO * WO;

constexpr int TH = 16, TW = 26;    // output tile (h x w)
constexpr int NTH = 20, NTW = 13;  // 20*16 >= 314; 13*26 >= 314
constexpr int OT = 13;             // t-outputs per half
constexpr int NBLK = B * 2 * NTH * NTW;   // 2080
constexpr int NPART = NBLK * 4;           // 8320 wave partials

typedef float v2f __attribute__((ext_vector_type(2)));

template<int N>
__device__ __forceinline__ float row_shr(float x) {
    // lane i (within its 16-lane DPP row) receives lane i-N; OOB -> 0
    return __int_as_float(__builtin_amdgcn_update_dpp(
        0, __float_as_int(x), 0x110 | N, 0xF, 0xF, true));
}

__device__ __forceinline__ unsigned pk_bf16(v2f v) {
    unsigned r;
    asm("v_cvt_pk_bf16_f32 %0, %1, %2" : "=v"(r) : "v"(v.x), "v"(v.y));
    return r;
}
__device__ __forceinline__ v2f unpk_bf16(unsigned u) {
    v2f r;
    r.x = __uint_as_float(u << 16);
    r.y = __uint_as_float(u & 0xffff0000u);
    return r;
}

__global__ __launch_bounds__(256) void ssim3d_fused(
    const float* __restrict__ pred,
    const float* __restrict__ targ,
    const float* __restrict__ drange,
    float* __restrict__ part)
{
    __shared__ float4 swv[4][2][10][16];   // 20480 B, wave-private regions

    const int bx = blockIdx.x;
    const int b  = bx / (2 * NTH * NTW);
    int rem      = bx % (2 * NTH * NTW);
    const int half = rem / (NTH * NTW);
    rem          = rem % (NTH * NTW);
    const int h0 = (rem / NTW) * TH;
    const int w0 = (rem % NTW) * TW;
    const int t0 = half * OT;

    const int tid  = threadIdx.x;
    const int wv   = tid >> 6;    // wave 0..3
    const int lane = tid & 63;
    const int ohl  = lane >> 4;   // 0..3: output row within wave
    const int k    = lane & 15;   // pair-column 0..15
    const int h0w  = h0 + 4 * wv; // wave's first output row

    const float* pb = pred + b * (T * H * W);
    const float* qb = targ + b * (T * H * W);

    // ---- wave-private staging: 160 items = 10 rows x 16 pair-cols ----
    // lane handles items lane, lane+64, (lane<32: lane+128)
    const bool has2 = (lane < 32);
    auto gofs = [&](int i) {
        int r = min(h0w + (i >> 4), H - 1);
        int c = min(w0 + 2 * (i & 15), W - 2);
        return r * W + c;
    };
    const int ga0 = gofs(lane);
    const int ga1 = gofs(lane + 64);
    const int ga2 = has2 ? gofs(lane + 128) : 0;

    float2 p0, q0, p1, q1, p2, q2;
    auto loadw = [&](int s) {
        const int so = (t0 + s) * (H * W);
        p0 = *reinterpret_cast<const float2*>(pb + so + ga0);
        q0 = *reinterpret_cast<const float2*>(qb + so + ga0);
        p1 = *reinterpret_cast<const float2*>(pb + so + ga1);
        q1 = *reinterpret_cast<const float2*>(qb + so + ga1);
        if (has2) {
            p2 = *reinterpret_cast<const float2*>(pb + so + ga2);
            q2 = *reinterpret_cast<const float2*>(qb + so + ga2);
        }
    };
    auto commitw = [&](int buf) {
        swv[wv][buf][ohl][k]     = make_float4(p0.x, p0.y, q0.x, q0.y);
        swv[wv][buf][4 + ohl][k] = make_float4(p1.x, p1.y, q1.x, q1.y);
        if (has2)
            swv[wv][buf][8 + ohl][k] = make_float4(p2.x, p2.y, q2.x, q2.y);
    };

    // ---- output mapping: thread k emits local cols 2k-6 (even), 2k-5 (odd)
    const bool vh = (h0w + ohl < HO);
    const bool k3 = (k >= 3);
    const bool vE = k3 && vh && (w0 + 2 * k - 6 < WO);
    const bool vO = k3 && vh && (w0 + 2 * k - 5 < WO);

    const float dr  = drange[b];
    const float C1s = (0.01f * dr) * (0.01f * dr);
    const float C2s = (0.03f * dr) * (0.03f * dr);
    const float inv  = 1.0f / (float)NPIX;
    const float covn = (float)NPIX / (float)(NPIX - 1);
    const v2f invv  = {inv, inv};
    const v2f C1vv  = {C1s, C1s};
    const v2f C2vv  = {C2s, C2s};
    const v2f covnv = {covn, covn};
    const v2f c2cov = {2.f * covn, 2.f * covn};

    unsigned rg[4][7];   // bf16x2-packed temporal ring
    v2f tEO[4];
#pragma unroll
    for (int f = 0; f < 4; ++f) {
        tEO[f] = (v2f){0.f, 0.f};
#pragma unroll
        for (int j = 0; j < 7; ++j) rg[f][j] = 0u;
    }
    float loss = 0.f;

    // ---- one slice; jj and flags compile-time at every call site ----
    auto slice = [&](int s, int jj, bool doEmit, bool doCommit, bool doPrefetch) {
        if (doCommit)  commitw((s + 1) & 1);  // regs loaded at slice s-1
        if (doPrefetch) loadw(s + 2);         // consumed at slice s+1

        // ---- per-thread pair-colsum: cols (2k,2k+1), rows ohl..ohl+6 ----
        const int bs = s & 1;
        v2f c0 = {0.f, 0.f}, c1v = {0.f, 0.f}, c2 = {0.f, 0.f}, c3 = {0.f, 0.f};
#pragma unroll
        for (int dy = 0; dy < 7; ++dy) {
            float4 v = swv[wv][bs][ohl + dy][k];
            v2f vp = {v.x, v.y};
            v2f vq = {v.z, v.w};
            c0 += vp;
            c1v += vq;
            c2 = __builtin_elementwise_fma(vp, vp, c2);
            c2 = __builtin_elementwise_fma(vq, vq, c2);
            c3 = __builtin_elementwise_fma(vp, vq, c3);
        }

        // ---- in-register w-gather via DPP row_shr ----
        v2f sv[4];
        {
            v2f cf[4] = {c0, c1v, c2, c3};
#pragma unroll
            for (int f = 0; f < 4; ++f) {
                float ps = cf[f].x + cf[f].y;
                float t1 = ps + row_shr<1>(ps);
                float s8 = t1 + row_shr<2>(t1);      // pairs k-3..k
                float eL = row_shr<3>(cf[f].x);      // col 2k-6
                sv[f].x = s8 - cf[f].y;              // cols 2k-6..2k (even)
                sv[f].y = s8 - eL;                   // cols 2k-5..2k+1 (odd)
            }
        }

        // ---- temporal 7-ring (slot jj = s % 7), bf16x2-packed ----
#pragma unroll
        for (int f = 0; f < 4; ++f) {
            unsigned nw = pk_bf16(sv[f]);
            v2f svr = unpk_bf16(nw);      // the value actually accumulated
            v2f old = unpk_bf16(rg[f][jj]);
            tEO[f] += svr - old;
            rg[f][jj] = nw;
        }

        // ---- SSIM on packed (E,O), emit for t_out = t0 + s - 6 ----
        if (doEmit) {
            v2f ux  = tEO[0] * invv;
            v2f uy  = tEO[1] * invv;
            v2f u2  = tEO[2] * invv;
            v2f uxy = tEO[3] * invv;
            v2f m   = __builtin_elementwise_fma(-ux, uy, uxy);
            v2f A2  = __builtin_elementwise_fma(c2cov, m, C2vv);
            v2f nb  = __builtin_elementwise_fma(-ux, ux, u2);
            nb      = __builtin_elementwise_fma(-uy, uy, nb);
            v2f B2  = __builtin_elementwise_fma(covnv, nb, C2vv);
            v2f ux2 = ux + ux;
            v2f A1  = __builtin_elementwise_fma(ux2, uy, C1vv);
            v2f B1  = __builtin_elementwise_fma(
                          ux, ux, __builtin_elementwise_fma(uy, uy, C1vv));
            v2f num = A1 * A2;
            v2f den = B1 * B2;
            float sx = __fdividef(num.x, den.x);
            float sy = __fdividef(num.y, den.y);
            if (vE) loss += 1.f - sx;
            if (vO) loss += 1.f - sy;
        }
    };

    // ---- prologue (wave-local, no barrier) ----
    loadw(0);
    commitw(0);
    loadw(1);

    // slices 0..6: ring fill, emit only at s==6 (s+2 <= 8 < 19)
#pragma unroll
    for (int jj = 0; jj < 7; ++jj)
        slice(jj, jj, jj == 6, true, true);

    // slices 7..13: unconditional (s+2 <= 15 < 19)
#pragma unroll
    for (int jj = 0; jj < 7; ++jj)
        slice(7 + jj, jj, true, true, true);

    // tail: s = 14..18 (flags compile-time)
    slice(14, 0, true, true, true);    // commit 15, load 16
    slice(15, 1, true, true, true);    // commit 16, load 17
    slice(16, 2, true, true, true);    // commit 17, load 18
    slice(17, 3, true, true, false);   // commit 18
    slice(18, 4, true, false, false);

    // ---- wave reduction -> plain store of wave partial (NO atomics) ----
    for (int off = 32; off > 0; off >>= 1)
        loss += __shfl_down(loss, off, 64);
    if (lane == 0) part[bx * 4 + wv] = loss;
}

__global__ __launch_bounds__(256) void ssim3d_finalize(
    const float* __restrict__ part,
    float* __restrict__ out)
{
    __shared__ float ws[4];
    const int tid = threadIdx.x;
    float s = 0.f;
    for (int i = tid; i < NPART; i += 256)
        s += part[i];
    for (int off = 32; off > 0; off >>= 1)
        s += __shfl_down(s, off, 64);
    if ((tid & 63) == 0) ws[tid >> 6] = s;
    __syncthreads();
    if (tid == 0)
        out[0] = (ws[0] + ws[1] + ws[2] + ws[3]) / (float)NOUT;
}

extern "C" void kernel_launch(void* const* d_in, const int* in_sizes, int n_in,
                              void* d_out, int out_size, void* d_ws, size_t ws_size,
                              hipStream_t stream)
{
    const float* pred   = (const float*)d_in[0];
    const float* targ   = (const float*)d_in[1];
    const float* drange = (const float*)d_in[2];
    float* out  = (float*)d_out;
    float* part = (float*)d_ws;   // 8320 floats = 33.3 KB of scratch

    ssim3d_fused<<<NBLK, 256, 0, stream>>>(pred, targ, drange, part);
    ssim3d_finalize<<<1, 256, 0, stream>>>(part, out);
}